// Round 2
// baseline (87.822 us; speedup 1.0000x reference)
//
#include <hip/hip_runtime.h>
#include <hip/hip_bf16.h>
#include <math.h>

#define NC 32
#define NA 48
#define NSP 4
#define NPAIRS 10          // NSP*(NSP+1)/2
#define NSHFR 16
#define NSHFA 4
#define NSHFZ 8
#define RAD_LEN (NSP * NSHFR)            // 64
#define ANG_LEN (NPAIRS * NSHFA * NSHFZ) // 320
#define AEV_LEN (RAD_LEN + ANG_LEN)      // 384

#define RCR 5.2f
#define RCA 3.5f

// One block (1 wave, 64 threads) per atom-center (c, i).
__global__ __launch_bounds__(64)
void aev_kernel(const float* __restrict__ coords,   // (NC, NA, 3)
                const float* __restrict__ etaR_p,   // (1,)
                const float* __restrict__ shfR,     // (16,)
                const float* __restrict__ etaA_p,   // (1,)
                const float* __restrict__ zeta_p,   // (1,)
                const float* __restrict__ shfA,     // (4,)
                const float* __restrict__ shfZ,     // (8,)
                const int*   __restrict__ species,  // (NC, NA)
                float* __restrict__ out)            // (NC, NA, 384) fp32
{
    const int tid = threadIdx.x;
    const int blk = blockIdx.x;          // c*NA + i
    const int c = blk / NA;
    const int i = blk - c * NA;

    __shared__ float sx[NA], sy[NA], sz[NA];
    __shared__ int   ssp[NA];
    __shared__ float sd[NA];             // distance i->j (self = 1e9)
    __shared__ int   nb[NA];             // angular neighbor list (slots)
    __shared__ float nbd[NA];
    __shared__ int   nM;
    __shared__ float aev[AEV_LEN];
    __shared__ float sCz[NSHFZ], sSz[NSHFZ];
    __shared__ float sShfA[NSHFA];

    // ---- phase A: zero accumulators, load conformer into LDS ----
    for (int f = tid; f < AEV_LEN; f += 64) aev[f] = 0.0f;
    if (tid == 0) nM = 0;
    if (tid < NA) {
        const int g = (c * NA + tid) * 3;
        sx[tid] = coords[g + 0];
        sy[tid] = coords[g + 1];
        sz[tid] = coords[g + 2];
        ssp[tid] = species[c * NA + tid];
    }
    if (tid < NSHFZ) {
        float v = shfZ[tid];
        sCz[tid] = cosf(v);
        sSz[tid] = sinf(v);
    }
    if (tid >= 8 && tid < 8 + NSHFA) sShfA[tid - 8] = shfA[tid - 8];
    __syncthreads();

    const float xi = sx[i], yi = sy[i], zi = sz[i];
    const float etaR = etaR_p[0];
    const float etaA = etaA_p[0];
    const float zeta = zeta_p[0];

    // ---- phase B: distances + angular neighbor list ----
    if (tid < NA) {
        float dx = sx[tid] - xi, dy = sy[tid] - yi, dz = sz[tid] - zi;
        float d = sqrtf(dx * dx + dy * dy + dz * dz);
        if (tid == i) d = 1.0e9f;        // exclude self everywhere
        sd[tid] = d;
        if (tid != i && d <= RCA) {
            int slot = atomicAdd(&nM, 1);
            nb[slot]  = tid;
            nbd[slot] = d;
        }
    }
    __syncthreads();

    // ---- phase C: radial. thread tid owns feature (s = tid>>4, r = tid&15) ----
    {
        const int s = tid >> 4;
        const int r = tid & 15;
        const float shfr = shfR[r];
        float acc = 0.0f;
        for (int j = 0; j < NA; ++j) {
            float d = sd[j];
            if (d <= RCR && ssp[j] == s) {
                float fc = 0.5f * cosf(d * (float)(M_PI / 5.2)) + 0.5f;
                float diff = d - shfr;
                acc += 0.25f * expf(-etaR * diff * diff) * fc;
            }
        }
        aev[tid] = acc;   // sole writer of [0,64)
    }

    // ---- phase D: angular over unordered neighbor pairs ----
    const int M = nM;
    const int npairs = (M * (M - 1)) >> 1;
    for (int p = tid; p < npairs; p += 64) {
        // map linear p -> (a,b), a<b over M slots
        int a = 0, rem = p, rowlen = M - 1;
        while (rem >= rowlen) { rem -= rowlen; --rowlen; ++a; }
        int b = a + 1 + rem;

        const int j = nb[a], k = nb[b];
        const float d1 = nbd[a], d2 = nbd[b];
        float v1x = sx[j] - xi, v1y = sy[j] - yi, v1z = sz[j] - zi;
        float v2x = sx[k] - xi, v2y = sy[k] - yi, v2z = sz[k] - zi;
        float dot = v1x * v2x + v1y * v2y + v1z * v2z;
        float cosang = dot / fmaxf(d1 * d2, 1e-10f);
        cosang = fminf(1.0f, fmaxf(-1.0f, cosang));
        // angle = acos(0.95*cosang); cos(angle - s) = ct*cos(s) + st*sin(s)
        float ct = 0.95f * cosang;
        float st = sqrtf(fmaxf(0.0f, 1.0f - ct * ct));
        float fc1 = 0.5f * cosf(d1 * (float)(M_PI / 3.5)) + 0.5f;
        float fc2 = 0.5f * cosf(d2 * (float)(M_PI / 3.5)) + 0.5f;
        float fcj12 = fc1 * fc2;
        float ebase = 0.5f * (d1 + d2);

        int s1 = ssp[j], s2 = ssp[k];
        int lo = min(s1, s2), hi = max(s1, s2);
        int pidx = lo * NSP - ((lo * (lo - 1)) >> 1) + (hi - lo);

        float f2v[NSHFA];
        #pragma unroll
        for (int a2 = 0; a2 < NSHFA; ++a2) {
            float e = ebase - sShfA[a2];
            f2v[a2] = expf(-etaA * e * e);
        }
        float* basep = &aev[RAD_LEN + pidx * (NSHFA * NSHFZ)];
        #pragma unroll
        for (int z = 0; z < NSHFZ; ++z) {
            float cz = ct * sCz[z] + st * sSz[z];
            float f1 = powf(0.5f * (1.0f + cz), zeta);
            float t = 2.0f * f1 * fcj12;
            #pragma unroll
            for (int a2 = 0; a2 < NSHFA; ++a2) {
                atomicAdd(&basep[a2 * NSHFZ + z], t * f2v[a2]);
            }
        }
    }
    __syncthreads();

    // ---- epilogue: fp32 LDS -> fp32 global ----
    float* o = out + (size_t)blk * AEV_LEN;
    for (int f = tid; f < AEV_LEN; f += 64) {
        o[f] = aev[f];
    }
}

extern "C" void kernel_launch(void* const* d_in, const int* in_sizes, int n_in,
                              void* d_out, int out_size, void* d_ws, size_t ws_size,
                              hipStream_t stream) {
    const float* coords = (const float*)d_in[0];
    const float* etaR   = (const float*)d_in[1];
    const float* shfR   = (const float*)d_in[2];
    const float* etaA   = (const float*)d_in[3];
    const float* zeta   = (const float*)d_in[4];
    const float* shfA   = (const float*)d_in[5];
    const float* shfZ   = (const float*)d_in[6];
    const int*   spec   = (const int*)d_in[7];
    float* out = (float*)d_out;

    aev_kernel<<<NC * NA, 64, 0, stream>>>(coords, etaR, shfR, etaA, zeta,
                                           shfA, shfZ, spec, out);
}

// Round 3
// 82.521 us; speedup vs baseline: 1.0642x; 1.0642x over previous
//
#include <hip/hip_runtime.h>
#include <hip/hip_bf16.h>
#include <math.h>

#define NC 32
#define NA 48
#define NSP 4
#define NPAIRS 10          // NSP*(NSP+1)/2
#define NSHFR 16
#define NSHFA 4
#define NSHFZ 8
#define RAD_LEN (NSP * NSHFR)            // 64
#define ANG_LEN (NPAIRS * NSHFA * NSHFZ) // 320
#define AEV_LEN (RAD_LEN + ANG_LEN)      // 384

#define RCR 5.2f
#define RCA 3.5f

// One block (1 wave, 64 threads) per atom-center (c, i).
__global__ __launch_bounds__(64)
void aev_kernel(const float* __restrict__ coords,   // (NC, NA, 3)
                const float* __restrict__ etaR_p,   // (1,)
                const float* __restrict__ shfR,     // (16,)
                const float* __restrict__ etaA_p,   // (1,)
                const float* __restrict__ zeta_p,   // (1,)
                const float* __restrict__ shfA,     // (4,)
                const float* __restrict__ shfZ,     // (8,)
                const int*   __restrict__ species,  // (NC, NA)
                float* __restrict__ out)            // (NC, NA, 384) fp32
{
    const int tid = threadIdx.x;
    const int blk = blockIdx.x;          // c*NA + i
    const int c = blk / NA;
    const int i = blk - c * NA;

    __shared__ float sx[NA], sy[NA], sz[NA];
    __shared__ int   ssp[NA];
    // radial neighbor list (d <= RCR, j != i)
    __shared__ float rd[NA], rfc[NA];
    __shared__ int   rsp[NA];
    __shared__ int   nR;
    // angular neighbor list (d <= RCA, j != i)
    __shared__ float ax[NA], ay[NA], az[NA], ad[NA], afc[NA];
    __shared__ int   asp[NA];
    __shared__ int   nM;
    // per-pair chunk scratch (64 pairs at a time)
    __shared__ float pct[64], pst[64], pfc[64];
    __shared__ float pf2[NSHFA][64];
    __shared__ int   ppidx[64];
    // constants
    __shared__ float sCz[NSHFZ], sSz[NSHFZ], sShfA[NSHFA], sShfR[NSHFR];
    alignas(16) __shared__ float aev[AEV_LEN];

    // ---- phase A: zero accumulators, load constants + conformer ----
    for (int f = tid; f < AEV_LEN; f += 64) aev[f] = 0.0f;
    if (tid == 0) { nR = 0; nM = 0; }
    if (tid < NA) {
        const int g = (c * NA + tid) * 3;
        sx[tid] = coords[g + 0];
        sy[tid] = coords[g + 1];
        sz[tid] = coords[g + 2];
        ssp[tid] = species[c * NA + tid];
    }
    if (tid < NSHFZ) {
        float v = shfZ[tid];
        sCz[tid] = cosf(v);
        sSz[tid] = sinf(v);
    }
    if (tid >= 8 && tid < 8 + NSHFA)  sShfA[tid - 8]  = shfA[tid - 8];
    if (tid >= 16 && tid < 16 + NSHFR) sShfR[tid - 16] = shfR[tid - 16];
    __syncthreads();

    const float xi = sx[i], yi = sy[i], zi = sz[i];
    const float etaR = etaR_p[0];
    const float etaA = etaA_p[0];
    const float zeta = zeta_p[0];
    const bool  zeta32 = (zeta == 32.0f);

    // ---- phase B: distances, cutoffs, compacted neighbor lists ----
    if (tid < NA && tid != i) {
        float dx = sx[tid] - xi, dy = sy[tid] - yi, dz = sz[tid] - zi;
        float d = sqrtf(dx * dx + dy * dy + dz * dz);
        if (d <= RCR) {
            float fcR = 0.5f * cosf(d * (float)(M_PI / 5.2)) + 0.5f;
            int slot = atomicAdd(&nR, 1);
            rd[slot] = d; rfc[slot] = fcR; rsp[slot] = ssp[tid];
        }
        if (d <= RCA) {
            float fcA = 0.5f * cosf(d * (float)(M_PI / 3.5)) + 0.5f;
            int slot = atomicAdd(&nM, 1);
            ax[slot] = dx; ay[slot] = dy; az[slot] = dz;
            ad[slot] = d; afc[slot] = fcA; asp[slot] = ssp[tid];
        }
    }
    __syncthreads();

    // ---- phase C: radial, task-parallel over (neighbor, shift) ----
    {
        const int ntask = nR * NSHFR;
        for (int t = tid; t < ntask; t += 64) {
            int j = t >> 4, r = t & 15;
            float diff = rd[j] - sShfR[r];
            float v = 0.25f * __expf(-etaR * diff * diff) * rfc[j];
            atomicAdd(&aev[rsp[j] * NSHFR + r], v);
        }
    }

    // ---- phase D: angular, two-stage, chunked over pairs ----
    const int M = nM;
    const int npairs = (M * (M - 1)) >> 1;
    for (int p0 = 0; p0 < npairs; p0 += 64) {
        const int chunk = min(64, npairs - p0);
        if (tid < chunk) {
            int p = p0 + tid;
            // linear p -> (a,b), a<b over M slots
            int a = 0, rem = p, rowlen = M - 1;
            while (rem >= rowlen) { rem -= rowlen; --rowlen; ++a; }
            int b = a + 1 + rem;

            float d1 = ad[a], d2 = ad[b];
            float dot = ax[a] * ax[b] + ay[a] * ay[b] + az[a] * az[b];
            float cosang = dot / fmaxf(d1 * d2, 1e-10f);
            cosang = fminf(1.0f, fmaxf(-1.0f, cosang));
            float ct = 0.95f * cosang;
            pct[tid] = ct;
            pst[tid] = sqrtf(fmaxf(0.0f, 1.0f - ct * ct));
            pfc[tid] = afc[a] * afc[b];
            int s1 = asp[a], s2 = asp[b];
            int lo = min(s1, s2), hi = max(s1, s2);
            ppidx[tid] = lo * NSP - ((lo * (lo - 1)) >> 1) + (hi - lo);
            float ebase = 0.5f * (d1 + d2);
            #pragma unroll
            for (int a2 = 0; a2 < NSHFA; ++a2) {
                float e = ebase - sShfA[a2];
                pf2[a2][tid] = __expf(-etaA * e * e);
            }
        }
        __syncthreads();

        const int ntask = chunk * NSHFZ;
        for (int t = tid; t < ntask; t += 64) {
            int p = t >> 3, z = t & 7;
            float ct = pct[p], st = pst[p];
            float cz = ct * sCz[z] + st * sSz[z];
            float u = 0.5f * (1.0f + cz);
            float f1;
            if (zeta32) {
                float u2 = u * u, u4 = u2 * u2, u8 = u4 * u4, u16 = u8 * u8;
                f1 = u16 * u16;
            } else {
                f1 = __powf(u, zeta);
            }
            float tmul = 2.0f * f1 * pfc[p];
            float* basep = &aev[RAD_LEN + ppidx[p] * (NSHFA * NSHFZ) + z];
            #pragma unroll
            for (int a2 = 0; a2 < NSHFA; ++a2) {
                atomicAdd(&basep[a2 * NSHFZ], tmul * pf2[a2][p]);
            }
        }
        __syncthreads();
    }
    __syncthreads();

    // ---- epilogue: fp32 LDS -> fp32 global, float4 ----
    float4* o4 = (float4*)(out + (size_t)blk * AEV_LEN);
    const float4* a4 = (const float4*)aev;
    for (int f = tid; f < AEV_LEN / 4; f += 64) {
        o4[f] = a4[f];
    }
}

extern "C" void kernel_launch(void* const* d_in, const int* in_sizes, int n_in,
                              void* d_out, int out_size, void* d_ws, size_t ws_size,
                              hipStream_t stream) {
    const float* coords = (const float*)d_in[0];
    const float* etaR   = (const float*)d_in[1];
    const float* shfR   = (const float*)d_in[2];
    const float* etaA   = (const float*)d_in[3];
    const float* zeta   = (const float*)d_in[4];
    const float* shfA   = (const float*)d_in[5];
    const float* shfZ   = (const float*)d_in[6];
    const int*   spec   = (const int*)d_in[7];
    float* out = (float*)d_out;

    aev_kernel<<<NC * NA, 64, 0, stream>>>(coords, etaR, shfR, etaA, zeta,
                                           shfA, shfZ, spec, out);
}

// Round 4
// 81.249 us; speedup vs baseline: 1.0809x; 1.0157x over previous
//
#include <hip/hip_runtime.h>
#include <hip/hip_bf16.h>
#include <math.h>

#define NC 32
#define NA 48
#define NSP 4
#define NPAIRS 10          // NSP*(NSP+1)/2
#define NSHFR 16
#define NSHFA 4
#define NSHFZ 8
#define RAD_LEN (NSP * NSHFR)            // 64
#define ANG_LEN (NPAIRS * NSHFA * NSHFZ) // 320
#define AEV_LEN (RAD_LEN + ANG_LEN)      // 384

#define RCR 5.2f
#define RCA 3.5f
#define NT 128             // 2 waves per block, one atom-center per block

__global__ __launch_bounds__(NT)
void aev_kernel(const float* __restrict__ coords,   // (NC, NA, 3)
                const float* __restrict__ etaR_p,   // (1,)
                const float* __restrict__ shfR,     // (16,)
                const float* __restrict__ etaA_p,   // (1,)
                const float* __restrict__ zeta_p,   // (1,)
                const float* __restrict__ shfA,     // (4,)
                const float* __restrict__ shfZ,     // (8,)
                const int*   __restrict__ species,  // (NC, NA)
                float* __restrict__ out)            // (NC, NA, 384) fp32
{
    const int tid = threadIdx.x;
    const int blk = blockIdx.x;          // c*NA + i
    const int c = blk / NA;
    const int i = blk - c * NA;

    __shared__ float sx[NA], sy[NA], sz[NA];
    __shared__ int   ssp[NA];
    // radial neighbor list (d <= RCR, j != i)
    __shared__ float rd[NA], rfc[NA];
    __shared__ int   rsp[NA];
    __shared__ int   nR;
    // angular neighbor list (d <= RCA, j != i)
    __shared__ float ax[NA], ay[NA], az[NA], ad[NA], afc[NA];
    __shared__ int   asp[NA];
    __shared__ int   nM;
    // per-pair chunk scratch (NT pairs at a time)
    __shared__ float pct[NT], pst[NT], pfc[NT];
    __shared__ float pf2[NSHFA][NT];
    __shared__ int   ppidx[NT];
    // constants
    __shared__ float sCz[NSHFZ], sSz[NSHFZ], sShfA[NSHFA], sShfR[NSHFR];
    alignas(16) __shared__ float aev[AEV_LEN];

    // ---- phase A: zero accumulators, load constants + conformer ----
    for (int f = tid; f < AEV_LEN; f += NT) aev[f] = 0.0f;
    if (tid == 0) { nR = 0; nM = 0; }
    if (tid < NA) {
        const int g = (c * NA + tid) * 3;
        sx[tid] = coords[g + 0];
        sy[tid] = coords[g + 1];
        sz[tid] = coords[g + 2];
        ssp[tid] = species[c * NA + tid];
    }
    if (tid >= 48 && tid < 48 + NSHFZ) {
        float v = shfZ[tid - 48];
        sCz[tid - 48] = __cosf(v);
        sSz[tid - 48] = __sinf(v);
    }
    if (tid >= 56 && tid < 56 + NSHFA)  sShfA[tid - 56] = shfA[tid - 56];
    if (tid >= 64 && tid < 64 + NSHFR)  sShfR[tid - 64] = shfR[tid - 64];
    __syncthreads();

    const float xi = sx[i], yi = sy[i], zi = sz[i];
    const float etaR = etaR_p[0];
    const float etaA = etaA_p[0];
    const float zeta = zeta_p[0];
    const bool  zeta32 = (zeta == 32.0f);

    // ---- phase B: distances, cutoffs, compacted neighbor lists ----
    if (tid < NA && tid != i) {
        float dx = sx[tid] - xi, dy = sy[tid] - yi, dz = sz[tid] - zi;
        float d = sqrtf(dx * dx + dy * dy + dz * dz);
        if (d <= RCR) {
            float fcR = 0.5f * __cosf(d * (float)(M_PI / 5.2)) + 0.5f;
            int slot = atomicAdd(&nR, 1);
            rd[slot] = d; rfc[slot] = fcR; rsp[slot] = ssp[tid];
        }
        if (d <= RCA) {
            float fcA = 0.5f * __cosf(d * (float)(M_PI / 3.5)) + 0.5f;
            int slot = atomicAdd(&nM, 1);
            ax[slot] = dx; ay[slot] = dy; az[slot] = dz;
            ad[slot] = d; afc[slot] = fcA; asp[slot] = ssp[tid];
        }
    }
    __syncthreads();

    // ---- phase C: radial, task-parallel over (neighbor, shift) ----
    {
        const int ntask = nR * NSHFR;
        for (int t = tid; t < ntask; t += NT) {
            int j = t >> 4, r = t & 15;
            float diff = rd[j] - sShfR[r];
            float v = 0.25f * __expf(-etaR * diff * diff) * rfc[j];
            atomicAdd(&aev[rsp[j] * NSHFR + r], v);
        }
    }

    // ---- phase D: angular, two-stage, chunked over pairs ----
    const int M = nM;
    const int npairs = (M * (M - 1)) >> 1;
    for (int p0 = 0; p0 < npairs; p0 += NT) {
        const int chunk = min(NT, npairs - p0);
        if (tid < chunk) {
            int p = p0 + tid;
            // linear p -> (a,b), a<b over M slots
            int a = 0, rem = p, rowlen = M - 1;
            while (rem >= rowlen) { rem -= rowlen; --rowlen; ++a; }
            int b = a + 1 + rem;

            float d1 = ad[a], d2 = ad[b];
            float dot = ax[a] * ax[b] + ay[a] * ay[b] + az[a] * az[b];
            float cosang = dot / fmaxf(d1 * d2, 1e-10f);
            cosang = fminf(1.0f, fmaxf(-1.0f, cosang));
            float ct = 0.95f * cosang;
            pct[tid] = ct;
            pst[tid] = sqrtf(fmaxf(0.0f, 1.0f - ct * ct));
            pfc[tid] = afc[a] * afc[b];
            int s1 = asp[a], s2 = asp[b];
            int lo = min(s1, s2), hi = max(s1, s2);
            ppidx[tid] = lo * NSP - ((lo * (lo - 1)) >> 1) + (hi - lo);
            float ebase = 0.5f * (d1 + d2);
            #pragma unroll
            for (int a2 = 0; a2 < NSHFA; ++a2) {
                float e = ebase - sShfA[a2];
                pf2[a2][tid] = __expf(-etaA * e * e);
            }
        }
        __syncthreads();

        const int ntask = chunk * NSHFZ;
        for (int t = tid; t < ntask; t += NT) {
            int p = t >> 3, z = t & 7;
            float ct = pct[p], st = pst[p];
            float cz = ct * sCz[z] + st * sSz[z];
            float u = 0.5f * (1.0f + cz);
            float f1;
            if (zeta32) {
                float u2 = u * u, u4 = u2 * u2, u8 = u4 * u4, u16 = u8 * u8;
                f1 = u16 * u16;
            } else {
                f1 = __powf(u, zeta);
            }
            float tmul = 2.0f * f1 * pfc[p];
            float* basep = &aev[RAD_LEN + ppidx[p] * (NSHFA * NSHFZ) + z];
            #pragma unroll
            for (int a2 = 0; a2 < NSHFA; ++a2) {
                atomicAdd(&basep[a2 * NSHFZ], tmul * pf2[a2][p]);
            }
        }
        __syncthreads();
    }
    __syncthreads();

    // ---- epilogue: fp32 LDS -> fp32 global, float4 ----
    float4* o4 = (float4*)(out + (size_t)blk * AEV_LEN);
    const float4* a4 = (const float4*)aev;
    for (int f = tid; f < AEV_LEN / 4; f += NT) {
        o4[f] = a4[f];
    }
}

extern "C" void kernel_launch(void* const* d_in, const int* in_sizes, int n_in,
                              void* d_out, int out_size, void* d_ws, size_t ws_size,
                              hipStream_t stream) {
    const float* coords = (const float*)d_in[0];
    const float* etaR   = (const float*)d_in[1];
    const float* shfR   = (const float*)d_in[2];
    const float* etaA   = (const float*)d_in[3];
    const float* zeta   = (const float*)d_in[4];
    const float* shfA   = (const float*)d_in[5];
    const float* shfZ   = (const float*)d_in[6];
    const int*   spec   = (const int*)d_in[7];
    float* out = (float*)d_out;

    aev_kernel<<<NC * NA, NT, 0, stream>>>(coords, etaR, shfR, etaA, zeta,
                                           shfA, shfZ, spec, out);
}